// Round 2
// baseline (6562.005 us; speedup 1.0000x reference)
//
#include <hip/hip_runtime.h>
#include <hip/hip_bf16.h>

// ---- problem dims (fixed) ----
#define NCLS 4
#define BS   16
#define NT   32
#define OC   12
#define HW   4096
#define PIX  65536
#define STATE 786432        // PIX*OC
#define BANK  3145728       // NCLS*STATE
#define NBLK 1024
#define NGRP 64             // 16 blocks per barrier group

typedef short bf16x8 __attribute__((ext_vector_type(8)));
typedef float f32x4  __attribute__((ext_vector_type(4)));

// jax.nn.hard_sigmoid = relu6(x+3)/6
__device__ __forceinline__ float hsig(float v){
    return fminf(fmaxf((v + 3.0f) * (1.0f/6.0f), 0.0f), 1.0f);
}
__device__ __forceinline__ short f2bf(float f){
    union { __hip_bfloat16 h; short s; } u;
    u.h = __float2bfloat16(f);   // RNE
    return u.s;
}

// =====================================================================
// Weight repack (verified R2): fragment-order bf16.
// wgt[cell][tap][kb][nt][lane], elem j = B[k=kb*32+(lane>>4)*8+j][n=nt*16+(lane&15)]
// =====================================================================
__global__ __launch_bounds__(256) void repack_kernel(
    const float* __restrict__ Wxg, const float* __restrict__ Whg,
    const float* __restrict__ Wxc, const float* __restrict__ Whc,
    bf16x8* __restrict__ wgt)
{
    int id = blockIdx.x * 256 + threadIdx.x;    // < 6912
    if (id >= 6912) return;
    int cell = id / 3456;
    int rem  = id - cell * 3456;
    int tap  = rem / 384;  rem -= tap * 384;
    int kb   = rem / 192;  rem -= kb * 192;
    int nt   = rem / 64;
    int lane = rem - nt * 64;
    int quad = lane >> 4;
    int n    = nt * 16 + (lane & 15);
    union { bf16x8 v; short s[8]; } o;
    #pragma unroll
    for (int j = 0; j < 8; ++j){
        int k = kb * 32 + quad * 8 + j;
        float f = 0.0f;
        if (cell == 0){
            if (k < 48)      f = Wxg[(tap*48 + k)*48 + n];
            else if (k < 60) f = Whg[(tap*12 + (k-48))*48 + n];
        } else {
            if (k < 24)      f = Wxc[(tap*24 + k)*48 + n];
            else if (k < 36) f = Whc[(tap*12 + (k-24))*48 + n];
        }
        o.s[j] = f2bf(f);
    }
    wgt[id] = o.v;
}

// LDS halo: 4 k-planes (one kb half at a time): halo[q][r][c][8ch] bf16,
// q in [0,4), r in [0,3), c in [0,66). 12672 B -> 4 blocks/CU fits easily.
#define HALO_SHORTS (4*198*8)     // 6336 shorts = 12672 B

// XCD-aware row swizzle: XCD j gets a CONTIGUOUS band of 128 rows (2 images).
__device__ __forceinline__ int row_swizzle(int bid){
    return ((bid & 7) << 7) | (bid >> 3);
}

// =====================================================================
// Software grid barrier (graph-capture safe; no cooperative launch).
// Two-level: 64 group counters (128B apart) -> top counter -> generation.
// All fences are agent-scope (__threadfence) for cross-XCD visibility.
// =====================================================================
__device__ __forceinline__ void gbar(int* bar, int bid){
    __syncthreads();
    if (threadIdx.x == 0){
        int* grp = bar + (bid >> 4) * 32;      // one cacheline per group
        int* top = bar + NGRP * 32;
        int* gen = top + 32;
        __threadfence();                        // release this block's writes
        int g = __hip_atomic_load(gen, __ATOMIC_RELAXED, __HIP_MEMORY_SCOPE_AGENT);
        bool wait = true;
        if (__hip_atomic_fetch_add(grp, 1, __ATOMIC_RELAXED, __HIP_MEMORY_SCOPE_AGENT) == 15){
            __hip_atomic_store(grp, 0, __ATOMIC_RELAXED, __HIP_MEMORY_SCOPE_AGENT);
            __threadfence();
            if (__hip_atomic_fetch_add(top, 1, __ATOMIC_RELAXED, __HIP_MEMORY_SCOPE_AGENT) == NGRP-1){
                __hip_atomic_store(top, 0, __ATOMIC_RELAXED, __HIP_MEMORY_SCOPE_AGENT);
                __threadfence();
                __hip_atomic_store(gen, g+1, __ATOMIC_RELAXED, __HIP_MEMORY_SCOPE_AGENT);
                wait = false;
            }
        }
        if (wait){
            while (__hip_atomic_load(gen, __ATOMIC_RELAXED, __HIP_MEMORY_SCOPE_AGENT) <= g)
                __builtin_amdgcn_s_sleep(2);
        }
        __threadfence();                        // acquire remote writes
    }
    __syncthreads();
}

// =====================================================================
// Fused persistent kernel: all 32 timesteps, gen+class phases separated
// by software grid barriers. gen_c / class_c / out-sum live in registers.
// =====================================================================
__global__ __launch_bounds__(256, 4) void fused_kernel(
    const float* __restrict__ xall,    // (BS,NT,HW,12) f32
    const int*   __restrict__ ids,
    short* __restrict__ bank,          // (PIX*48) bf16 flat (raw-reshape alias)
    short* __restrict__ genh0,
    short* __restrict__ genh1,
    short* __restrict__ htmp0,
    short* __restrict__ htmp1,
    const bf16x8* __restrict__ wgt,    // gen at +0, class at +3456
    const float* __restrict__ bias_g,
    const float* __restrict__ bias_c,
    int* __restrict__ bar,             // barrier state (zeroed by launcher)
    float* __restrict__ out)           // (PIX,12) f32, written once at end
{
    __shared__ __align__(16) short halo[HALO_SHORTS];
    const int tid = threadIdx.x;
    const int bid = blockIdx.x;
    const int rb  = row_swizzle(bid);
    const int p0  = rb << 6;
    const int b   = p0 >> 12;
    const int y   = (p0 >> 6) & 63;
    const int lane = tid & 63;
    const int w    = tid >> 6;
    const int m    = lane & 15;
    const int quad = lane >> 4;
    const int colbase = 16*w + m;
    const int pbase   = p0 + 16*w;
    const bf16x8* wgt_cls = wgt + 3456;

    // ---- persistent per-thread state (same off = pbase*12 + lane*3+s every t) ----
    float genc[3] = {0.f, 0.f, 0.f};
    float clsc[NCLS][3];
    #pragma unroll
    for (int q = 0; q < NCLS; ++q){
        clsc[q][0] = 0.f; clsc[q][1] = 0.f; clsc[q][2] = 0.f;
    }
    float osum[3] = {0.f, 0.f, 0.f};

    // ---- zero-init bank + genh0 (everything else is written before read) ----
    {
        const uint4 z = make_uint4(0u,0u,0u,0u);
        uint4* bp = (uint4*)bank;                    // 393216 uint4
        for (int idx = bid*256 + tid; idx < 393216; idx += 262144)
            bp[idx] = z;
        uint4* gp = (uint4*)genh0;                   // 98304 uint4
        for (int idx = bid*256 + tid; idx < 98304; idx += 262144)
            gp[idx] = z;
    }
    gbar(bar, bid);

    for (int t = 0; t < NT; ++t){
        const short* hin  = (t & 1) ? genh1 : genh0;
        short*       hnew = (t & 1) ? genh0 : genh1;
        const short* htp  = (t & 1) ? htmp0 : htmp1;   // htmp_prev
        short*       htn  = (t & 1) ? htmp1 : htmp0;   // htmp_new
        const int cid   = ids[t];
        const int cprev = (t > 0) ? ids[t-1] : -1;

        // ======================= GEN phase =======================
        {
            const bool slotmatch = (cprev >= 0) && ((b >> 2) == cprev);
            const short* bsrc = slotmatch ? htp : bank;

            const int i = tid;
            const bool active = (i < 198);
            int r  = i / 66, c = i - r * 66;
            int yy = y + r - 1, xx = c - 1;
            bool valid = active & (yy >= 0) & (yy < 64) & (xx >= 0) & (xx < 64);
            int p  = (b << 12) + (yy << 6) + xx;
            int pb = slotmatch ? (p & 16383) : p;
            uint4 bk[6]; uint2 h0, h1, h2;
            #pragma unroll
            for (int q = 0; q < 6; ++q) bk[q] = make_uint4(0u,0u,0u,0u);
            h0 = make_uint2(0u,0u); h1 = h0; h2 = h0;
            if (valid){
                const short* bp = bsrc + pb*48;
                #pragma unroll
                for (int q = 0; q < 6; ++q) bk[q] = *(const uint4*)(bp + q*8);
                h0 = *(const uint2*)(hin + p*12);
                h1 = *(const uint2*)(hin + p*12 + 4);
                h2 = *(const uint2*)(hin + p*12 + 8);
                if (slotmatch && r == 1){          // own row: refresh bank
                    #pragma unroll
                    for (int q = 0; q < 6; ++q)
                        *(uint4*)(bank + p*48 + q*8) = bk[q];
                }
            }
            // ---- kb=0 planes: bank ch 0..31 ----
            if (active){
                #pragma unroll
                for (int q = 0; q < 4; ++q)
                    *(uint4*)&halo[(q*198 + i)*8] = bk[q];
            }
            __syncthreads();

            f32x4 acc0 = {0.f,0.f,0.f,0.f};
            f32x4 acc1 = acc0, acc2 = acc0;

            // ---- MFMA kb=0 ----
            #pragma unroll
            for (int ky = 0; ky < 3; ++ky){
                #pragma unroll
                for (int kx = 0; kx < 3; ++kx){
                    const int tap = ky*3 + kx;
                    const bf16x8 a = *(const bf16x8*)
                        &halo[((quad*198) + ky*66 + colbase + kx)*8];
                    const bf16x8* wp = wgt + ((tap*2 + 0)*3)*64 + lane;
                    acc0 = __builtin_amdgcn_mfma_f32_16x16x32_bf16(a, wp[0],   acc0, 0,0,0);
                    acc1 = __builtin_amdgcn_mfma_f32_16x16x32_bf16(a, wp[64],  acc1, 0,0,0);
                    acc2 = __builtin_amdgcn_mfma_f32_16x16x32_bf16(a, wp[128], acc2, 0,0,0);
                }
            }
            __syncthreads();

            // ---- kb=1 planes: bank ch 32..47, h 0..11 ----
            if (active){
                *(uint4*)&halo[(0*198 + i)*8] = bk[4];
                *(uint4*)&halo[(1*198 + i)*8] = bk[5];
                union { uint2 u2[2]; uint4 u4; } p2, p3;
                p2.u2[0] = h0; p2.u2[1] = h1;
                p3.u2[0] = h2; p3.u2[1] = make_uint2(0u,0u);
                *(uint4*)&halo[(2*198 + i)*8] = p2.u4;
                *(uint4*)&halo[(3*198 + i)*8] = p3.u4;
            }
            __syncthreads();

            // ---- MFMA kb=1 ----
            #pragma unroll
            for (int ky = 0; ky < 3; ++ky){
                #pragma unroll
                for (int kx = 0; kx < 3; ++kx){
                    const int tap = ky*3 + kx;
                    const bf16x8 a = *(const bf16x8*)
                        &halo[((quad*198) + ky*66 + colbase + kx)*8];
                    const bf16x8* wp = wgt + ((tap*2 + 1)*3)*64 + lane;
                    acc0 = __builtin_amdgcn_mfma_f32_16x16x32_bf16(a, wp[0],   acc0, 0,0,0);
                    acc1 = __builtin_amdgcn_mfma_f32_16x16x32_bf16(a, wp[64],  acc1, 0,0,0);
                    acc2 = __builtin_amdgcn_mfma_f32_16x16x32_bf16(a, wp[128], acc2, 0,0,0);
                }
            }
            __syncthreads();

            // ---- epilogue: z transpose through LDS + LSTM math ----
            float* zw = ((float*)halo) + w * 768;
            #pragma unroll
            for (int r2 = 0; r2 < 4; ++r2){
                zw[(quad*4 + r2)*48 +      m] = acc0[r2];
                zw[(quad*4 + r2)*48 + 16 + m] = acc1[r2];
                zw[(quad*4 + r2)*48 + 32 + m] = acc2[r2];
            }
            __syncthreads();
            #pragma unroll
            for (int s = 0; s < 3; ++s){
                int idx = lane*3 + s;
                int px  = idx / 12;
                int j   = idx - px*12;
                float zi = zw[px*48 +      j] + bias_g[j];
                float zf = zw[px*48 + 12 + j] + bias_g[12 + j];
                float zg = zw[px*48 + 24 + j] + bias_g[24 + j];
                float zo = zw[px*48 + 36 + j] + bias_g[36 + j];
                float cold = genc[s];
                float cn = hsig(zf)*cold + hsig(zi)*tanhf(zg);
                genc[s] = cn;
                hnew[pbase*12 + idx] = f2bf(hsig(zo)*tanhf(cn));
            }
        }
        gbar(bar, bid);

        // ======================= CLASS phase =======================
        {
            const short* chs   = bank + (size_t)cid * STATE;
            const float* frame = xall + (size_t)(b*NT + t) * (HW*12);

            const int i = tid;
            const bool active = (i < 198);
            int r  = i / 66, c = i - r * 66;
            int yy = y + r - 1, xx = c - 1;
            bool valid = active & (yy >= 0) & (yy < 64) & (xx >= 0) & (xx < 64);
            int pl = (yy << 6) + xx;
            int p  = (b << 12) + pl;
            float4 f0, f1, f2;
            f0 = make_float4(0.f,0.f,0.f,0.f); f1 = f0; f2 = f0;
            uint2 g0, g1, g2, s0, s1, s2;
            g0 = make_uint2(0u,0u); g1 = g0; g2 = g0; s0 = g0; s1 = g0; s2 = g0;
            if (valid){
                f0 = *(const float4*)(frame + pl*12);
                f1 = *(const float4*)(frame + pl*12 + 4);
                f2 = *(const float4*)(frame + pl*12 + 8);
                g0 = *(const uint2*)(hnew + p*12);
                g1 = *(const uint2*)(hnew + p*12 + 4);
                g2 = *(const uint2*)(hnew + p*12 + 8);
                s0 = *(const uint2*)(chs + p*12);
                s1 = *(const uint2*)(chs + p*12 + 4);
                s2 = *(const uint2*)(chs + p*12 + 8);
            }
            // ---- kb=0 planes: frame 0..11 | gen_h 0..11 | class_h 0..7 ----
            if (active){
                union { uint4 u4; uint2 u2[2]; short sh[8]; } pk;
                pk.sh[0]=f2bf(f0.x); pk.sh[1]=f2bf(f0.y); pk.sh[2]=f2bf(f0.z); pk.sh[3]=f2bf(f0.w);
                pk.sh[4]=f2bf(f1.x); pk.sh[5]=f2bf(f1.y); pk.sh[6]=f2bf(f1.z); pk.sh[7]=f2bf(f1.w);
                *(uint4*)&halo[(0*198 + i)*8] = pk.u4;
                pk.sh[0]=f2bf(f2.x); pk.sh[1]=f2bf(f2.y); pk.sh[2]=f2bf(f2.z); pk.sh[3]=f2bf(f2.w);
                pk.u2[1] = g0;
                *(uint4*)&halo[(1*198 + i)*8] = pk.u4;
                pk.u2[0] = g1; pk.u2[1] = g2;
                *(uint4*)&halo[(2*198 + i)*8] = pk.u4;
                pk.u2[0] = s0; pk.u2[1] = s1;
                *(uint4*)&halo[(3*198 + i)*8] = pk.u4;
            }
            __syncthreads();

            f32x4 acc0 = {0.f,0.f,0.f,0.f};
            f32x4 acc1 = acc0, acc2 = acc0;

            // ---- MFMA kb=0 ----
            #pragma unroll
            for (int ky = 0; ky < 3; ++ky){
                #pragma unroll
                for (int kx = 0; kx < 3; ++kx){
                    const int tap = ky*3 + kx;
                    const bf16x8 a = *(const bf16x8*)
                        &halo[((quad*198) + ky*66 + colbase + kx)*8];
                    const bf16x8* wp = wgt_cls + ((tap*2 + 0)*3)*64 + lane;
                    acc0 = __builtin_amdgcn_mfma_f32_16x16x32_bf16(a, wp[0],   acc0, 0,0,0);
                    acc1 = __builtin_amdgcn_mfma_f32_16x16x32_bf16(a, wp[64],  acc1, 0,0,0);
                    acc2 = __builtin_amdgcn_mfma_f32_16x16x32_bf16(a, wp[128], acc2, 0,0,0);
                }
            }
            __syncthreads();

            // ---- kb=1 planes: class_h 8..11, rest zero ----
            if (active){
                union { uint4 u4; uint2 u2[2]; } p0k;
                p0k.u2[0] = s2; p0k.u2[1] = make_uint2(0u,0u);
                uint4 z = make_uint4(0u,0u,0u,0u);
                *(uint4*)&halo[(0*198 + i)*8] = p0k.u4;
                *(uint4*)&halo[(1*198 + i)*8] = z;
                *(uint4*)&halo[(2*198 + i)*8] = z;
                *(uint4*)&halo[(3*198 + i)*8] = z;
            }
            __syncthreads();

            // ---- MFMA kb=1 ----
            #pragma unroll
            for (int ky = 0; ky < 3; ++ky){
                #pragma unroll
                for (int kx = 0; kx < 3; ++kx){
                    const int tap = ky*3 + kx;
                    const bf16x8 a = *(const bf16x8*)
                        &halo[((quad*198) + ky*66 + colbase + kx)*8];
                    const bf16x8* wp = wgt_cls + ((tap*2 + 1)*3)*64 + lane;
                    acc0 = __builtin_amdgcn_mfma_f32_16x16x32_bf16(a, wp[0],   acc0, 0,0,0);
                    acc1 = __builtin_amdgcn_mfma_f32_16x16x32_bf16(a, wp[64],  acc1, 0,0,0);
                    acc2 = __builtin_amdgcn_mfma_f32_16x16x32_bf16(a, wp[128], acc2, 0,0,0);
                }
            }
            __syncthreads();

            // ---- epilogue ----
            float* zw = ((float*)halo) + w * 768;
            #pragma unroll
            for (int r2 = 0; r2 < 4; ++r2){
                zw[(quad*4 + r2)*48 +      m] = acc0[r2];
                zw[(quad*4 + r2)*48 + 16 + m] = acc1[r2];
                zw[(quad*4 + r2)*48 + 32 + m] = acc2[r2];
            }
            __syncthreads();
            #pragma unroll
            for (int s = 0; s < 3; ++s){
                int idx = lane*3 + s;
                int px  = idx / 12;
                int j   = idx - px*12;
                float zi = zw[px*48 +      j] + bias_c[j];
                float zf = zw[px*48 + 12 + j] + bias_c[12 + j];
                float zg = zw[px*48 + 24 + j] + bias_c[24 + j];
                float zo = zw[px*48 + 36 + j] + bias_c[36 + j];
                // class_c in registers; cid is wave-uniform -> static select
                float cold = 0.f;
                #pragma unroll
                for (int q = 0; q < NCLS; ++q) if (q == cid) cold = clsc[q][s];
                float cn = hsig(zf)*cold + hsig(zi)*tanhf(zg);
                #pragma unroll
                for (int q = 0; q < NCLS; ++q) if (q == cid) clsc[q][s] = cn;
                float h = hsig(zo)*tanhf(cn);
                htn[pbase*12 + idx] = f2bf(h);
                osum[s] += h;              // time-sum in fp32 (pre-rounding h)
            }
        }
        gbar(bar, bid);
    }

    // ---- final output write (full coverage, once) ----
    #pragma unroll
    for (int s = 0; s < 3; ++s)
        out[pbase*12 + lane*3 + s] = osum[s];
}

extern "C" void kernel_launch(void* const* d_in, const int* in_sizes, int n_in,
                              void* d_out, int out_size, void* d_ws, size_t ws_size,
                              hipStream_t stream)
{
    (void)in_sizes; (void)n_in; (void)out_size; (void)ws_size;
    const float* x    = (const float*)d_in[0];
    const int*   ids  = (const int*)  d_in[1];
    const float* Wxg  = (const float*)d_in[2];
    const float* Whg  = (const float*)d_in[3];
    const float* bg   = (const float*)d_in[4];
    const float* Wxc  = (const float*)d_in[5];
    const float* Whc  = (const float*)d_in[6];
    const float* bc   = (const float*)d_in[7];
    float* out = (float*)d_out;

    char* base = (char*)d_ws;
    short*  bank  = (short*) (base);                 // 6,291,456 B
    short*  genh0 = (short*) (base + 6291456);       // 1,572,864
    short*  genh1 = (short*) (base + 7864320);       // 1,572,864
    short*  htmp0 = (short*) (base + 9437184);       // 1,572,864
    short*  htmp1 = (short*) (base + 11010048);      // 1,572,864
    bf16x8* wgt   = (bf16x8*)(base + 12582912);      // 110,592
    int*    bar   = (int*)   (base + 12693504);      // 16,384 (barrier state)

    // barrier state must start zeroed; captured into the graph -> reset per replay
    hipMemsetAsync(bar, 0, 16384, stream);

    repack_kernel<<<27, 256, 0, stream>>>(Wxg, Whg, Wxc, Whc, wgt);

    fused_kernel<<<NBLK, 256, 0, stream>>>(x, ids, bank, genh0, genh1,
                                           htmp0, htmp1, wgt, bg, bc, bar, out);
}

// Round 4
// 2947.917 us; speedup vs baseline: 2.2260x; 2.2260x over previous
//
#include <hip/hip_runtime.h>
#include <hip/hip_bf16.h>

// ---- problem dims (fixed) ----
#define NCLS 4
#define BS   16
#define NT   32
#define OC   12
#define HW   4096
#define PIX  65536
#define STATE 786432        // PIX*OC
#define BANK  3145728       // NCLS*STATE
#define NBLK 1024
#define NGRP 64             // 16 blocks per barrier group

typedef short bf16x8 __attribute__((ext_vector_type(8)));
typedef float f32x4  __attribute__((ext_vector_type(4)));
typedef unsigned long long u64;

// jax.nn.hard_sigmoid = relu6(x+3)/6
__device__ __forceinline__ float hsig(float v){
    return fminf(fmaxf((v + 3.0f) * (1.0f/6.0f), 0.0f), 1.0f);
}
__device__ __forceinline__ short f2bf(float f){
    union { __hip_bfloat16 h; short s; } u;
    u.h = __float2bfloat16(f);   // RNE
    return u.s;
}

// ---- device-coherent (agent-scope, sc1) 8-byte accesses: serviced at the
// Infinity Cache, bypassing the non-coherent per-XCD L1/L2. ----
__device__ __forceinline__ u64 cld(const void* p){
    return __hip_atomic_load((const u64*)p, __ATOMIC_RELAXED, __HIP_MEMORY_SCOPE_AGENT);
}
__device__ __forceinline__ void cst(void* p, u64 v){
    __hip_atomic_store((u64*)p, v, __ATOMIC_RELAXED, __HIP_MEMORY_SCOPE_AGENT);
}
// order point: wait until my outstanding vmem ops (incl. sc1 stores/RMWs)
// have completed at the coherence point. NO cache writeback/invalidate.
__device__ __forceinline__ void vdrain(){
    asm volatile("s_waitcnt vmcnt(0)" ::: "memory");
}

// =====================================================================
// Weight repack (verified R2): fragment-order bf16.
// wgt[cell][tap][kb][nt][lane], elem j = B[k=kb*32+(lane>>4)*8+j][n=nt*16+(lane&15)]
// =====================================================================
__global__ __launch_bounds__(256) void repack_kernel(
    const float* __restrict__ Wxg, const float* __restrict__ Whg,
    const float* __restrict__ Wxc, const float* __restrict__ Whc,
    bf16x8* __restrict__ wgt)
{
    int id = blockIdx.x * 256 + threadIdx.x;    // < 6912
    if (id >= 6912) return;
    int cell = id / 3456;
    int rem  = id - cell * 3456;
    int tap  = rem / 384;  rem -= tap * 384;
    int kb   = rem / 192;  rem -= kb * 192;
    int nt   = rem / 64;
    int lane = rem - nt * 64;
    int quad = lane >> 4;
    int n    = nt * 16 + (lane & 15);
    union { bf16x8 v; short s[8]; } o;
    #pragma unroll
    for (int j = 0; j < 8; ++j){
        int k = kb * 32 + quad * 8 + j;
        float f = 0.0f;
        if (cell == 0){
            if (k < 48)      f = Wxg[(tap*48 + k)*48 + n];
            else if (k < 60) f = Whg[(tap*12 + (k-48))*48 + n];
        } else {
            if (k < 24)      f = Wxc[(tap*24 + k)*48 + n];
            else if (k < 36) f = Whc[(tap*12 + (k-24))*48 + n];
        }
        o.s[j] = f2bf(f);
    }
    wgt[id] = o.v;
}

// LDS halo: 4 k-planes (one kb half at a time): halo[q][r][c][8ch] bf16,
// q in [0,4), r in [0,3), c in [0,66). 12672 B.
#define HALO_SHORTS (4*198*8)     // 6336 shorts = 12672 B

// XCD-aware row swizzle: XCD j gets a CONTIGUOUS band of 128 rows (2 images).
__device__ __forceinline__ int row_swizzle(int bid){
    return ((bid & 7) << 7) | (bid >> 3);
}

// =====================================================================
// Software grid barrier. Coherence of DATA is per-access (sc1); ordering of
// the COUNTER protocol is enforced with leader-only vmcnt(0) drains between
// counter ops (relaxed vmem ops to different addresses may complete out of
// order -> R3's fence-free version could lose a group-counter reset behind
// the gen bump => deadlock. vdrain() restores order at ~ns cost, no cache ops).
// =====================================================================
__device__ __forceinline__ void gbar(int* bar, int bid){
    vdrain();                 // each wave: my sc1 data stores are at IC
    __syncthreads();
    if (threadIdx.x == 0){
        int* grp = bar + (bid >> 4) * 32;      // one cacheline per group
        int* top = bar + NGRP * 32;
        int* gen = top + 32;
        int g = __hip_atomic_load(gen, __ATOMIC_RELAXED, __HIP_MEMORY_SCOPE_AGENT);
        vdrain();             // g observed before my arrival can complete
        bool wait = true;
        if (__hip_atomic_fetch_add(grp, 1, __ATOMIC_RELAXED, __HIP_MEMORY_SCOPE_AGENT) == 15){
            vdrain();
            __hip_atomic_store(grp, 0, __ATOMIC_RELAXED, __HIP_MEMORY_SCOPE_AGENT);
            vdrain();         // reset visible BEFORE top increment
            if (__hip_atomic_fetch_add(top, 1, __ATOMIC_RELAXED, __HIP_MEMORY_SCOPE_AGENT) == NGRP-1){
                vdrain();
                __hip_atomic_store(top, 0, __ATOMIC_RELAXED, __HIP_MEMORY_SCOPE_AGENT);
                vdrain();     // top reset visible BEFORE gen bump
                __hip_atomic_store(gen, g+1, __ATOMIC_RELAXED, __HIP_MEMORY_SCOPE_AGENT);
                wait = false;
            }
        }
        if (wait){
            int spins = 0;
            while (__hip_atomic_load(gen, __ATOMIC_RELAXED, __HIP_MEMORY_SCOPE_AGENT) <= g){
                __builtin_amdgcn_s_sleep(2);
                if (++spins > (1<<17)) break;   // watchdog: never fires if sound
            }
        }
    }
    __syncthreads();   // also a compiler memory barrier
}

// =====================================================================
// Fused persistent kernel: all 32 timesteps; gen_c / class_c / out-sum in
// registers; recurrent arrays accessed via coherent (sc1) u64 ops only.
// =====================================================================
__global__ __launch_bounds__(256, 4) void fused_kernel(
    const float* __restrict__ xall,    // (BS,NT,HW,12) f32
    const int*   __restrict__ ids,
    short* __restrict__ bank,          // (PIX*48) bf16 flat (raw-reshape alias)
    short* __restrict__ genh0,
    short* __restrict__ genh1,
    short* __restrict__ htmp0,
    short* __restrict__ htmp1,
    const bf16x8* __restrict__ wgt,    // gen at +0, class at +3456
    const float* __restrict__ bias_g,
    const float* __restrict__ bias_c,
    int* __restrict__ bar,             // barrier state (zeroed by launcher)
    float* __restrict__ out)           // (PIX,12) f32, written once at end
{
    __shared__ __align__(16) short halo[HALO_SHORTS];
    __shared__ __align__(8)  short hrow[768];          // 64 px * 12 ch (one row)
    const int tid = threadIdx.x;
    const int bid = blockIdx.x;
    const int rb  = row_swizzle(bid);
    const int p0  = rb << 6;
    const int b   = p0 >> 12;
    const int y   = (p0 >> 6) & 63;
    const int lane = tid & 63;
    const int w    = tid >> 6;
    const int m    = lane & 15;
    const int quad = lane >> 4;
    const int colbase = 16*w + m;
    const bf16x8* wgt_cls = wgt + 3456;

    // ---- persistent per-thread state ----
    float genc[3] = {0.f, 0.f, 0.f};
    float clsc[NCLS][3];
    #pragma unroll
    for (int q = 0; q < NCLS; ++q){
        clsc[q][0] = 0.f; clsc[q][1] = 0.f; clsc[q][2] = 0.f;
    }
    float osum[3] = {0.f, 0.f, 0.f};

    // ---- zero-init bank + genh0 through the COHERENT path ----
    {
        u64* bp = (u64*)bank;                    // 786432 u64
        for (int idx = bid*256 + tid; idx < 786432; idx += 262144)
            cst(bp + idx, 0ull);
        u64* gp = (u64*)genh0;                   // 196608 u64
        for (int idx = bid*256 + tid; idx < 196608; idx += 262144)
            cst(gp + idx, 0ull);
    }
    gbar(bar, bid);

    for (int t = 0; t < NT; ++t){
        const short* hin  = (t & 1) ? genh1 : genh0;
        short*       hnew = (t & 1) ? genh0 : genh1;
        const short* htp  = (t & 1) ? htmp0 : htmp1;   // htmp_prev
        short*       htn  = (t & 1) ? htmp1 : htmp0;   // htmp_new
        const int cid   = ids[t];
        const int cprev = (t > 0) ? ids[t-1] : -1;

        // ======================= GEN phase =======================
        {
            const bool slotmatch = (cprev >= 0) && ((b >> 2) == cprev);
            const short* bsrc = slotmatch ? htp : bank;

            const int i = tid;
            const bool active = (i < 198);
            int r  = i / 66, c = i - r * 66;
            int yy = y + r - 1, xx = c - 1;
            bool valid = active & (yy >= 0) & (yy < 64) & (xx >= 0) & (xx < 64);
            int p  = (b << 12) + (yy << 6) + xx;
            int pb = slotmatch ? (p & 16383) : p;
            u64 bkq[12]; u64 h0q, h1q, h2q;
            #pragma unroll
            for (int q = 0; q < 12; ++q) bkq[q] = 0ull;
            h0q = 0ull; h1q = 0ull; h2q = 0ull;
            if (valid){
                const short* bp = bsrc + pb*48;
                #pragma unroll
                for (int q = 0; q < 12; ++q) bkq[q] = cld(bp + q*4);
                h0q = cld(hin + p*12);
                h1q = cld(hin + p*12 + 4);
                h2q = cld(hin + p*12 + 8);
                if (slotmatch && r == 1){          // own row: refresh bank
                    #pragma unroll
                    for (int q = 0; q < 12; ++q)
                        cst(bank + p*48 + q*4, bkq[q]);
                }
            }
            // ---- kb=0 planes: bank ch 0..31 ----
            if (active){
                #pragma unroll
                for (int q = 0; q < 4; ++q){
                    union { uint4 v; u64 q2[2]; } t2;
                    t2.q2[0] = bkq[2*q]; t2.q2[1] = bkq[2*q+1];
                    *(uint4*)&halo[(q*198 + i)*8] = t2.v;
                }
            }
            __syncthreads();

            f32x4 acc0 = {0.f,0.f,0.f,0.f};
            f32x4 acc1 = acc0, acc2 = acc0;

            // ---- MFMA kb=0 ----
            #pragma unroll
            for (int ky = 0; ky < 3; ++ky){
                #pragma unroll
                for (int kx = 0; kx < 3; ++kx){
                    const int tap = ky*3 + kx;
                    const bf16x8 a = *(const bf16x8*)
                        &halo[((quad*198) + ky*66 + colbase + kx)*8];
                    const bf16x8* wp = wgt + ((tap*2 + 0)*3)*64 + lane;
                    acc0 = __builtin_amdgcn_mfma_f32_16x16x32_bf16(a, wp[0],   acc0, 0,0,0);
                    acc1 = __builtin_amdgcn_mfma_f32_16x16x32_bf16(a, wp[64],  acc1, 0,0,0);
                    acc2 = __builtin_amdgcn_mfma_f32_16x16x32_bf16(a, wp[128], acc2, 0,0,0);
                }
            }
            __syncthreads();

            // ---- kb=1 planes: bank ch 32..47, h 0..11 ----
            if (active){
                union { uint4 v; u64 q2[2]; } t2;
                t2.q2[0] = bkq[8];  t2.q2[1] = bkq[9];
                *(uint4*)&halo[(0*198 + i)*8] = t2.v;
                t2.q2[0] = bkq[10]; t2.q2[1] = bkq[11];
                *(uint4*)&halo[(1*198 + i)*8] = t2.v;
                t2.q2[0] = h0q; t2.q2[1] = h1q;
                *(uint4*)&halo[(2*198 + i)*8] = t2.v;
                t2.q2[0] = h2q; t2.q2[1] = 0ull;
                *(uint4*)&halo[(3*198 + i)*8] = t2.v;
            }
            __syncthreads();

            // ---- MFMA kb=1 ----
            #pragma unroll
            for (int ky = 0; ky < 3; ++ky){
                #pragma unroll
                for (int kx = 0; kx < 3; ++kx){
                    const int tap = ky*3 + kx;
                    const bf16x8 a = *(const bf16x8*)
                        &halo[((quad*198) + ky*66 + colbase + kx)*8];
                    const bf16x8* wp = wgt + ((tap*2 + 1)*3)*64 + lane;
                    acc0 = __builtin_amdgcn_mfma_f32_16x16x32_bf16(a, wp[0],   acc0, 0,0,0);
                    acc1 = __builtin_amdgcn_mfma_f32_16x16x32_bf16(a, wp[64],  acc1, 0,0,0);
                    acc2 = __builtin_amdgcn_mfma_f32_16x16x32_bf16(a, wp[128], acc2, 0,0,0);
                }
            }
            __syncthreads();

            // ---- epilogue: z transpose through LDS + LSTM math ----
            float* zw = ((float*)halo) + w * 768;
            #pragma unroll
            for (int r2 = 0; r2 < 4; ++r2){
                zw[(quad*4 + r2)*48 +      m] = acc0[r2];
                zw[(quad*4 + r2)*48 + 16 + m] = acc1[r2];
                zw[(quad*4 + r2)*48 + 32 + m] = acc2[r2];
            }
            __syncthreads();
            #pragma unroll
            for (int s = 0; s < 3; ++s){
                int idx = lane*3 + s;
                int px  = idx / 12;
                int j   = idx - px*12;
                float zi = zw[px*48 +      j] + bias_g[j];
                float zf = zw[px*48 + 12 + j] + bias_g[12 + j];
                float zg = zw[px*48 + 24 + j] + bias_g[24 + j];
                float zo = zw[px*48 + 36 + j] + bias_g[36 + j];
                float cold = genc[s];
                float cn = hsig(zf)*cold + hsig(zi)*tanhf(zg);
                genc[s] = cn;
                hrow[w*192 + idx] = f2bf(hsig(zo)*tanhf(cn));
            }
            __syncthreads();
            if (tid < 192)
                cst(((u64*)(hnew + (size_t)p0*12)) + tid, ((const u64*)hrow)[tid]);
        }
        gbar(bar, bid);

        // ======================= CLASS phase =======================
        {
            const short* chs   = bank + (size_t)cid * STATE;
            const float* frame = xall + (size_t)(b*NT + t) * (HW*12);

            const int i = tid;
            const bool active = (i < 198);
            int r  = i / 66, c = i - r * 66;
            int yy = y + r - 1, xx = c - 1;
            bool valid = active & (yy >= 0) & (yy < 64) & (xx >= 0) & (xx < 64);
            int pl = (yy << 6) + xx;
            int p  = (b << 12) + pl;
            float4 f0, f1, f2;
            f0 = make_float4(0.f,0.f,0.f,0.f); f1 = f0; f2 = f0;
            u64 g0q, g1q, g2q, s0q, s1q, s2q;
            g0q = 0ull; g1q = 0ull; g2q = 0ull; s0q = 0ull; s1q = 0ull; s2q = 0ull;
            if (valid){
                f0 = *(const float4*)(frame + pl*12);
                f1 = *(const float4*)(frame + pl*12 + 4);
                f2 = *(const float4*)(frame + pl*12 + 8);
                g0q = cld(hnew + p*12);
                g1q = cld(hnew + p*12 + 4);
                g2q = cld(hnew + p*12 + 8);
                s0q = cld(chs + p*12);
                s1q = cld(chs + p*12 + 4);
                s2q = cld(chs + p*12 + 8);
            }
            // ---- kb=0 planes: frame 0..11 | gen_h 0..11 | class_h 0..7 ----
            if (active){
                union { uint4 u4; u64 q2[2]; short sh[8]; } pk;
                pk.sh[0]=f2bf(f0.x); pk.sh[1]=f2bf(f0.y); pk.sh[2]=f2bf(f0.z); pk.sh[3]=f2bf(f0.w);
                pk.sh[4]=f2bf(f1.x); pk.sh[5]=f2bf(f1.y); pk.sh[6]=f2bf(f1.z); pk.sh[7]=f2bf(f1.w);
                *(uint4*)&halo[(0*198 + i)*8] = pk.u4;
                pk.sh[0]=f2bf(f2.x); pk.sh[1]=f2bf(f2.y); pk.sh[2]=f2bf(f2.z); pk.sh[3]=f2bf(f2.w);
                pk.q2[1] = g0q;
                *(uint4*)&halo[(1*198 + i)*8] = pk.u4;
                pk.q2[0] = g1q; pk.q2[1] = g2q;
                *(uint4*)&halo[(2*198 + i)*8] = pk.u4;
                pk.q2[0] = s0q; pk.q2[1] = s1q;
                *(uint4*)&halo[(3*198 + i)*8] = pk.u4;
            }
            __syncthreads();

            f32x4 acc0 = {0.f,0.f,0.f,0.f};
            f32x4 acc1 = acc0, acc2 = acc0;

            // ---- MFMA kb=0 ----
            #pragma unroll
            for (int ky = 0; ky < 3; ++ky){
                #pragma unroll
                for (int kx = 0; kx < 3; ++kx){
                    const int tap = ky*3 + kx;
                    const bf16x8 a = *(const bf16x8*)
                        &halo[((quad*198) + ky*66 + colbase + kx)*8];
                    const bf16x8* wp = wgt_cls + ((tap*2 + 0)*3)*64 + lane;
                    acc0 = __builtin_amdgcn_mfma_f32_16x16x32_bf16(a, wp[0],   acc0, 0,0,0);
                    acc1 = __builtin_amdgcn_mfma_f32_16x16x32_bf16(a, wp[64],  acc1, 0,0,0);
                    acc2 = __builtin_amdgcn_mfma_f32_16x16x32_bf16(a, wp[128], acc2, 0,0,0);
                }
            }
            __syncthreads();

            // ---- kb=1 planes: class_h 8..11, rest zero ----
            if (active){
                union { uint4 u4; u64 q2[2]; } p0k;
                p0k.q2[0] = s2q; p0k.q2[1] = 0ull;
                uint4 z = make_uint4(0u,0u,0u,0u);
                *(uint4*)&halo[(0*198 + i)*8] = p0k.u4;
                *(uint4*)&halo[(1*198 + i)*8] = z;
                *(uint4*)&halo[(2*198 + i)*8] = z;
                *(uint4*)&halo[(3*198 + i)*8] = z;
            }
            __syncthreads();

            // ---- MFMA kb=1 ----
            #pragma unroll
            for (int ky = 0; ky < 3; ++ky){
                #pragma unroll
                for (int kx = 0; kx < 3; ++kx){
                    const int tap = ky*3 + kx;
                    const bf16x8 a = *(const bf16x8*)
                        &halo[((quad*198) + ky*66 + colbase + kx)*8];
                    const bf16x8* wp = wgt_cls + ((tap*2 + 1)*3)*64 + lane;
                    acc0 = __builtin_amdgcn_mfma_f32_16x16x32_bf16(a, wp[0],   acc0, 0,0,0);
                    acc1 = __builtin_amdgcn_mfma_f32_16x16x32_bf16(a, wp[64],  acc1, 0,0,0);
                    acc2 = __builtin_amdgcn_mfma_f32_16x16x32_bf16(a, wp[128], acc2, 0,0,0);
                }
            }
            __syncthreads();

            // ---- epilogue ----
            float* zw = ((float*)halo) + w * 768;
            #pragma unroll
            for (int r2 = 0; r2 < 4; ++r2){
                zw[(quad*4 + r2)*48 +      m] = acc0[r2];
                zw[(quad*4 + r2)*48 + 16 + m] = acc1[r2];
                zw[(quad*4 + r2)*48 + 32 + m] = acc2[r2];
            }
            __syncthreads();
            #pragma unroll
            for (int s = 0; s < 3; ++s){
                int idx = lane*3 + s;
                int px  = idx / 12;
                int j   = idx - px*12;
                float zi = zw[px*48 +      j] + bias_c[j];
                float zf = zw[px*48 + 12 + j] + bias_c[12 + j];
                float zg = zw[px*48 + 24 + j] + bias_c[24 + j];
                float zo = zw[px*48 + 36 + j] + bias_c[36 + j];
                // class_c in registers; cid is wave-uniform -> static select
                float cold = 0.f;
                #pragma unroll
                for (int q = 0; q < NCLS; ++q) if (q == cid) cold = clsc[q][s];
                float cn = hsig(zf)*cold + hsig(zi)*tanhf(zg);
                #pragma unroll
                for (int q = 0; q < NCLS; ++q) if (q == cid) clsc[q][s] = cn;
                float h = hsig(zo)*tanhf(cn);
                hrow[w*192 + idx] = f2bf(h);
                osum[s] += h;              // time-sum in fp32 (pre-rounding h)
            }
            __syncthreads();
            if (tid < 192)
                cst(((u64*)(htn + (size_t)p0*12)) + tid, ((const u64*)hrow)[tid]);
        }
        if (t + 1 < NT) gbar(bar, bid);
    }

    // ---- final output write (full coverage, once; normal stores, kernel-end flush) ----
    const int pbase = p0 + 16*w;
    #pragma unroll
    for (int s = 0; s < 3; ++s)
        out[pbase*12 + lane*3 + s] = osum[s];
}

extern "C" void kernel_launch(void* const* d_in, const int* in_sizes, int n_in,
                              void* d_out, int out_size, void* d_ws, size_t ws_size,
                              hipStream_t stream)
{
    (void)in_sizes; (void)n_in; (void)out_size; (void)ws_size;
    const float* x    = (const float*)d_in[0];
    const int*   ids  = (const int*)  d_in[1];
    const float* Wxg  = (const float*)d_in[2];
    const float* Whg  = (const float*)d_in[3];
    const float* bg   = (const float*)d_in[4];
    const float* Wxc  = (const float*)d_in[5];
    const float* Whc  = (const float*)d_in[6];
    const float* bc   = (const float*)d_in[7];
    float* out = (float*)d_out;

    char* base = (char*)d_ws;
    short*  bank  = (short*) (base);                 // 6,291,456 B
    short*  genh0 = (short*) (base + 6291456);       // 1,572,864
    short*  genh1 = (short*) (base + 7864320);       // 1,572,864
    short*  htmp0 = (short*) (base + 9437184);       // 1,572,864
    short*  htmp1 = (short*) (base + 11010048);      // 1,572,864
    bf16x8* wgt   = (bf16x8*)(base + 12582912);      // 110,592
    int*    bar   = (int*)   (base + 12693504);      // 16,384 (barrier state)

    // barrier state must start zeroed; captured into the graph -> reset per replay
    // (gen counter is monotonic, so rocprof per-dispatch replay without the
    //  memset is also safe)
    hipMemsetAsync(bar, 0, 16384, stream);

    repack_kernel<<<27, 256, 0, stream>>>(Wxg, Whg, Wxc, Whc, wgt);

    fused_kernel<<<NBLK, 256, 0, stream>>>(x, ids, bank, genh0, genh1,
                                           htmp0, htmp1, wgt, bg, bc, bar, out);
}

// Round 6
// 2665.340 us; speedup vs baseline: 2.4620x; 1.1060x over previous
//
#include <hip/hip_runtime.h>
#include <hip/hip_bf16.h>

// ---- problem dims (fixed) ----
#define NCLS 4
#define BS   16
#define NT   32
#define OC   12
#define HW   4096
#define PIX  65536
#define STATE 786432        // PIX*OC
#define BANK  3145728       // NCLS*STATE
#define NBLK 1024
#define NGRP 64             // 16 blocks per barrier group

typedef short bf16x8 __attribute__((ext_vector_type(8)));
typedef float f32x4  __attribute__((ext_vector_type(4)));
typedef unsigned long long u64;

// jax.nn.hard_sigmoid = relu6(x+3)/6
__device__ __forceinline__ float hsig(float v){
    return fminf(fmaxf((v + 3.0f) * (1.0f/6.0f), 0.0f), 1.0f);
}
__device__ __forceinline__ short f2bf(float f){
    union { __hip_bfloat16 h; short s; } u;
    u.h = __float2bfloat16(f);   // RNE
    return u.s;
}

// ---- device-coherent (agent-scope, sc1) 8-byte accesses ----
__device__ __forceinline__ u64 cld(const void* p){
    return __hip_atomic_load((const u64*)p, __ATOMIC_RELAXED, __HIP_MEMORY_SCOPE_AGENT);
}
__device__ __forceinline__ void cst(void* p, u64 v){
    __hip_atomic_store((u64*)p, v, __ATOMIC_RELAXED, __HIP_MEMORY_SCOPE_AGENT);
}
__device__ __forceinline__ void vdrain(){
    asm volatile("s_waitcnt vmcnt(0)" ::: "memory");
}

// =====================================================================
// Weight repack (verified R2): fragment-order bf16.
// wgt[cell][tap][kb][nt][lane], elem j = B[k=kb*32+(lane>>4)*8+j][n=nt*16+(lane&15)]
// =====================================================================
__global__ __launch_bounds__(256) void repack_kernel(
    const float* __restrict__ Wxg, const float* __restrict__ Whg,
    const float* __restrict__ Wxc, const float* __restrict__ Whc,
    bf16x8* __restrict__ wgt)
{
    int id = blockIdx.x * 256 + threadIdx.x;    // < 6912
    if (id >= 6912) return;
    int cell = id / 3456;
    int rem  = id - cell * 3456;
    int tap  = rem / 384;  rem -= tap * 384;
    int kb   = rem / 192;  rem -= kb * 192;
    int nt   = rem / 64;
    int lane = rem - nt * 64;
    int quad = lane >> 4;
    int n    = nt * 16 + (lane & 15);
    union { bf16x8 v; short s[8]; } o;
    #pragma unroll
    for (int j = 0; j < 8; ++j){
        int k = kb * 32 + quad * 8 + j;
        float f = 0.0f;
        if (cell == 0){
            if (k < 48)      f = Wxg[(tap*48 + k)*48 + n];
            else if (k < 60) f = Whg[(tap*12 + (k-48))*48 + n];
        } else {
            if (k < 24)      f = Wxc[(tap*24 + k)*48 + n];
            else if (k < 36) f = Whc[(tap*12 + (k-24))*48 + n];
        }
        o.s[j] = f2bf(f);
    }
    wgt[id] = o.v;
}

// Pixel-major LDS halo: record = 72 shorts (144 B):
//   gen  : [0..47]=bank ch0..47 | [48..59]=h ch0..11 | [60..71]=0
//   class: [0..11]=frame | [12..23]=gen_h | [24..35]=class_h | [36..71]=0
// One record serves BOTH kb halves: kb0 frag = shorts quad*8, kb1 = 32+quad*8.
// 3 rows x 66 cols -> 14256 shorts = 28512 B (+1536 B hrow) -> 4 blocks/CU.
#define REC 72
#define HALO_SHORTS (3*66*REC)

// XCD-aware row swizzle: XCD j gets a CONTIGUOUS band of 128 rows (2 images).
__device__ __forceinline__ int row_swizzle(int bid){
    return ((bid & 7) << 7) | (bid >> 3);
}

// =====================================================================
// Software grid barrier (verified R4): counter ops ordered by leader-only
// vmcnt(0) drains; no cache writeback/invalidate anywhere.
// =====================================================================
__device__ __forceinline__ void gbar(int* bar, int bid){
    vdrain();                 // each wave: my sc1 data stores are at IC
    __syncthreads();
    if (threadIdx.x == 0){
        int* grp = bar + (bid >> 4) * 32;      // one cacheline per group
        int* top = bar + NGRP * 32;
        int* gen = top + 32;
        int g = __hip_atomic_load(gen, __ATOMIC_RELAXED, __HIP_MEMORY_SCOPE_AGENT);
        vdrain();             // g observed before my arrival can complete
        bool wait = true;
        if (__hip_atomic_fetch_add(grp, 1, __ATOMIC_RELAXED, __HIP_MEMORY_SCOPE_AGENT) == 15){
            vdrain();
            __hip_atomic_store(grp, 0, __ATOMIC_RELAXED, __HIP_MEMORY_SCOPE_AGENT);
            vdrain();         // reset visible BEFORE top increment
            if (__hip_atomic_fetch_add(top, 1, __ATOMIC_RELAXED, __HIP_MEMORY_SCOPE_AGENT) == NGRP-1){
                vdrain();
                __hip_atomic_store(top, 0, __ATOMIC_RELAXED, __HIP_MEMORY_SCOPE_AGENT);
                vdrain();     // top reset visible BEFORE gen bump
                __hip_atomic_store(gen, g+1, __ATOMIC_RELAXED, __HIP_MEMORY_SCOPE_AGENT);
                wait = false;
            }
        }
        if (wait){
            int spins = 0;
            while (__hip_atomic_load(gen, __ATOMIC_RELAXED, __HIP_MEMORY_SCOPE_AGENT) <= g){
                __builtin_amdgcn_s_sleep(2);
                if (++spins > (1<<17)) break;   // watchdog: never fires if sound
            }
        }
    }
    __syncthreads();
}

// =====================================================================
// Fused persistent kernel. Staging is COALESCED: threads cooperatively copy
// contiguous row spans (u64 lane-stride-8B) into pixel-major records.
// Sizes: bank slice/px = 48 sh = 12 u64; h slice/px = 12 sh = 3 u64.
// =====================================================================
__global__ __launch_bounds__(256, 4) void fused_kernel(
    const float* __restrict__ xall,    // (BS,NT,HW,12) f32
    const int*   __restrict__ ids,
    short* __restrict__ bank,          // (PIX*48) bf16 flat (raw-reshape alias)
    short* __restrict__ genh0,
    short* __restrict__ genh1,
    short* __restrict__ htmp0,
    short* __restrict__ htmp1,
    const bf16x8* __restrict__ wgt,    // gen at +0, class at +3456
    const float* __restrict__ bias_g,
    const float* __restrict__ bias_c,
    int* __restrict__ bar,             // barrier state (zeroed by launcher)
    float* __restrict__ out)           // (PIX,12) f32, written once at end
{
    __shared__ __align__(16) short halo[HALO_SHORTS];
    __shared__ __align__(8)  short hrow[768];          // 64 px * 12 ch (one row)
    const int tid = threadIdx.x;
    const int bid = blockIdx.x;
    const int rb  = row_swizzle(bid);
    const int p0  = rb << 6;
    const int b   = p0 >> 12;
    const int y   = (p0 >> 6) & 63;
    const int lane = tid & 63;
    const int w    = tid >> 6;
    const int m    = lane & 15;
    const int quad = lane >> 4;
    const int colbase = 16*w + m;
    const bf16x8* wgt_cls = wgt + 3456;

    // ---- persistent per-thread state ----
    float genc[3] = {0.f, 0.f, 0.f};
    float clsc[NCLS][3];
    #pragma unroll
    for (int q = 0; q < NCLS; ++q){
        clsc[q][0] = 0.f; clsc[q][1] = 0.f; clsc[q][2] = 0.f;
    }
    float osum[3] = {0.f, 0.f, 0.f};

    // ---- zero-init bank + genh0 through the COHERENT path ----
    {
        u64* bp = (u64*)bank;                    // 786432 u64
        for (int idx = bid*256 + tid; idx < 786432; idx += 262144)
            cst(bp + idx, 0ull);
        u64* gp = (u64*)genh0;                   // 196608 u64
        for (int idx = bid*256 + tid; idx < 196608; idx += 262144)
            cst(gp + idx, 0ull);
    }
    gbar(bar, bid);

    for (int t = 0; t < NT; ++t){
        const short* hin  = (t & 1) ? genh1 : genh0;
        short*       hnew = (t & 1) ? genh0 : genh1;
        const short* htp  = (t & 1) ? htmp0 : htmp1;   // htmp_prev
        short*       htn  = (t & 1) ? htmp1 : htmp0;   // htmp_new
        const int cid   = ids[t];
        const int cprev = (t > 0) ? ids[t-1] : -1;

        // ======================= GEN phase =======================
        {
            const bool slotmatch = (cprev >= 0) && ((b >> 2) == cprev);
            const short* bsrc = slotmatch ? htp : bank;

            // zero-fill all records (covers pads, edge cols, clamped rows)
            {
                const uint4 z = make_uint4(0u,0u,0u,0u);
                uint4* hz = (uint4*)halo;
                #pragma unroll
                for (int jj = 0; jj < 7; ++jj){
                    int j = jj*256 + tid;
                    if (j < HALO_SHORTS/8) hz[j] = z;
                }
            }
            __syncthreads();

            // bank rows: 3 x 64px x 12u64 = 2304 u64, coalesced
            #pragma unroll
            for (int jj = 0; jj < 9; ++jj){
                int j = jj*256 + tid;            // < 2304 exactly
                int r  = j / 768;
                int k  = j - r*768;              // u64 index within row span
                int yy = y + r - 1;
                if (yy >= 0 && yy <= 63){
                    int rowp  = (b << 12) + (yy << 6);
                    int pbrow = slotmatch ? (rowp & 16383) : rowp;
                    u64 v = cld(bsrc + pbrow*48 + k*4);
                    int px = k / 12, part = k - px*12;
                    *(u64*)&halo[(r*66 + px + 1)*REC + part*4] = v;
                    if (slotmatch && r == 1)      // own row: refresh bank
                        cst(bank + rowp*48 + k*4, v);
                }
            }
            // h rows: 3 x 64px x 3u64 = 576 u64, coalesced
            #pragma unroll
            for (int jj = 0; jj < 3; ++jj){
                int j = jj*256 + tid;
                if (j < 576){
                    int r  = j / 192;
                    int k  = j - r*192;
                    int yy = y + r - 1;
                    if (yy >= 0 && yy <= 63){
                        int rowp = (b << 12) + (yy << 6);
                        u64 v = cld(hin + rowp*12 + k*4);
                        int px = k / 3, sub = k - px*3;
                        *(u64*)&halo[(r*66 + px + 1)*REC + 48 + sub*4] = v;
                    }
                }
            }
            __syncthreads();

            f32x4 acc0 = {0.f,0.f,0.f,0.f};
            f32x4 acc1 = acc0, acc2 = acc0;

            // ---- MFMA, both kb halves from one staging ----
            #pragma unroll
            for (int ky = 0; ky < 3; ++ky){
                #pragma unroll
                for (int kx = 0; kx < 3; ++kx){
                    const int tap = ky*3 + kx;
                    const int rec = (ky*66 + colbase + kx)*REC;
                    const bf16x8 a0 = *(const bf16x8*)&halo[rec + quad*8];
                    const bf16x8 a1 = *(const bf16x8*)&halo[rec + 32 + quad*8];
                    const bf16x8* wp0 = wgt + ((tap*2 + 0)*3)*64 + lane;
                    const bf16x8* wp1 = wgt + ((tap*2 + 1)*3)*64 + lane;
                    acc0 = __builtin_amdgcn_mfma_f32_16x16x32_bf16(a0, wp0[0],   acc0, 0,0,0);
                    acc1 = __builtin_amdgcn_mfma_f32_16x16x32_bf16(a0, wp0[64],  acc1, 0,0,0);
                    acc2 = __builtin_amdgcn_mfma_f32_16x16x32_bf16(a0, wp0[128], acc2, 0,0,0);
                    acc0 = __builtin_amdgcn_mfma_f32_16x16x32_bf16(a1, wp1[0],   acc0, 0,0,0);
                    acc1 = __builtin_amdgcn_mfma_f32_16x16x32_bf16(a1, wp1[64],  acc1, 0,0,0);
                    acc2 = __builtin_amdgcn_mfma_f32_16x16x32_bf16(a1, wp1[128], acc2, 0,0,0);
                }
            }
            __syncthreads();

            // ---- epilogue: z transpose through LDS + LSTM math ----
            float* zw = ((float*)halo) + w * 768;
            #pragma unroll
            for (int r2 = 0; r2 < 4; ++r2){
                zw[(quad*4 + r2)*48 +      m] = acc0[r2];
                zw[(quad*4 + r2)*48 + 16 + m] = acc1[r2];
                zw[(quad*4 + r2)*48 + 32 + m] = acc2[r2];
            }
            __syncthreads();
            #pragma unroll
            for (int s = 0; s < 3; ++s){
                int idx = lane*3 + s;
                int px  = idx / 12;
                int j   = idx - px*12;
                float zi = zw[px*48 +      j] + bias_g[j];
                float zf = zw[px*48 + 12 + j] + bias_g[12 + j];
                float zg = zw[px*48 + 24 + j] + bias_g[24 + j];
                float zo = zw[px*48 + 36 + j] + bias_g[36 + j];
                float cold = genc[s];
                float cn = hsig(zf)*cold + hsig(zi)*tanhf(zg);
                genc[s] = cn;
                hrow[w*192 + idx] = f2bf(hsig(zo)*tanhf(cn));
            }
            __syncthreads();
            if (tid < 192)
                cst(((u64*)(hnew + (size_t)p0*12)) + tid, ((const u64*)hrow)[tid]);
        }
        gbar(bar, bid);

        // ======================= CLASS phase =======================
        {
            const short* chs   = bank + (size_t)cid * STATE;
            const float* frame = xall + (size_t)(b*NT + t) * (HW*12);

            // zero-fill
            {
                const uint4 z = make_uint4(0u,0u,0u,0u);
                uint4* hz = (uint4*)halo;
                #pragma unroll
                for (int jj = 0; jj < 7; ++jj){
                    int j = jj*256 + tid;
                    if (j < HALO_SHORTS/8) hz[j] = z;
                }
            }
            __syncthreads();

            // frame rows: 3 x 64px x 3float4 = 576 float4, coalesced + cvt
            #pragma unroll
            for (int jj = 0; jj < 3; ++jj){
                int j = jj*256 + tid;
                if (j < 576){
                    int r  = j / 192;
                    int k  = j - r*192;          // float4 index within row
                    int yy = y + r - 1;
                    if (yy >= 0 && yy <= 63){
                        float4 f = *(const float4*)(frame + yy*768 + k*4);
                        union { u64 q; short s[4]; } pk;
                        pk.s[0]=f2bf(f.x); pk.s[1]=f2bf(f.y);
                        pk.s[2]=f2bf(f.z); pk.s[3]=f2bf(f.w);
                        int px = k / 3, part = k - px*3;
                        *(u64*)&halo[(r*66 + px + 1)*REC + part*4] = pk.q;
                    }
                }
            }
            // gen_h rows (fresh): 576 u64
            #pragma unroll
            for (int jj = 0; jj < 3; ++jj){
                int j = jj*256 + tid;
                if (j < 576){
                    int r  = j / 192;
                    int k  = j - r*192;
                    int yy = y + r - 1;
                    if (yy >= 0 && yy <= 63){
                        int rowp = (b << 12) + (yy << 6);
                        u64 v = cld(hnew + rowp*12 + k*4);
                        int px = k / 3, sub = k - px*3;
                        *(u64*)&halo[(r*66 + px + 1)*REC + 12 + sub*4] = v;
                    }
                }
            }
            // class_h rows (slot cid): 576 u64
            #pragma unroll
            for (int jj = 0; jj < 3; ++jj){
                int j = jj*256 + tid;
                if (j < 576){
                    int r  = j / 192;
                    int k  = j - r*192;
                    int yy = y + r - 1;
                    if (yy >= 0 && yy <= 63){
                        int rowp = (b << 12) + (yy << 6);
                        u64 v = cld(chs + rowp*12 + k*4);
                        int px = k / 3, sub = k - px*3;
                        *(u64*)&halo[(r*66 + px + 1)*REC + 24 + sub*4] = v;
                    }
                }
            }
            __syncthreads();

            f32x4 acc0 = {0.f,0.f,0.f,0.f};
            f32x4 acc1 = acc0, acc2 = acc0;

            #pragma unroll
            for (int ky = 0; ky < 3; ++ky){
                #pragma unroll
                for (int kx = 0; kx < 3; ++kx){
                    const int tap = ky*3 + kx;
                    const int rec = (ky*66 + colbase + kx)*REC;
                    const bf16x8 a0 = *(const bf16x8*)&halo[rec + quad*8];
                    const bf16x8 a1 = *(const bf16x8*)&halo[rec + 32 + quad*8];
                    const bf16x8* wp0 = wgt_cls + ((tap*2 + 0)*3)*64 + lane;
                    const bf16x8* wp1 = wgt_cls + ((tap*2 + 1)*3)*64 + lane;
                    acc0 = __builtin_amdgcn_mfma_f32_16x16x32_bf16(a0, wp0[0],   acc0, 0,0,0);
                    acc1 = __builtin_amdgcn_mfma_f32_16x16x32_bf16(a0, wp0[64],  acc1, 0,0,0);
                    acc2 = __builtin_amdgcn_mfma_f32_16x16x32_bf16(a0, wp0[128], acc2, 0,0,0);
                    acc0 = __builtin_amdgcn_mfma_f32_16x16x32_bf16(a1, wp1[0],   acc0, 0,0,0);
                    acc1 = __builtin_amdgcn_mfma_f32_16x16x32_bf16(a1, wp1[64],  acc1, 0,0,0);
                    acc2 = __builtin_amdgcn_mfma_f32_16x16x32_bf16(a1, wp1[128], acc2, 0,0,0);
                }
            }
            __syncthreads();

            // ---- epilogue ----
            float* zw = ((float*)halo) + w * 768;
            #pragma unroll
            for (int r2 = 0; r2 < 4; ++r2){
                zw[(quad*4 + r2)*48 +      m] = acc0[r2];
                zw[(quad*4 + r2)*48 + 16 + m] = acc1[r2];
                zw[(quad*4 + r2)*48 + 32 + m] = acc2[r2];
            }
            __syncthreads();
            #pragma unroll
            for (int s = 0; s < 3; ++s){
                int idx = lane*3 + s;
                int px  = idx / 12;
                int j   = idx - px*12;
                float zi = zw[px*48 +      j] + bias_c[j];
                float zf = zw[px*48 + 12 + j] + bias_c[12 + j];
                float zg = zw[px*48 + 24 + j] + bias_c[24 + j];
                float zo = zw[px*48 + 36 + j] + bias_c[36 + j];
                float cold = 0.f;
                #pragma unroll
                for (int q = 0; q < NCLS; ++q) if (q == cid) cold = clsc[q][s];
                float cn = hsig(zf)*cold + hsig(zi)*tanhf(zg);
                #pragma unroll
                for (int q = 0; q < NCLS; ++q) if (q == cid) clsc[q][s] = cn;
                float h = hsig(zo)*tanhf(cn);
                hrow[w*192 + idx] = f2bf(h);
                osum[s] += h;              // time-sum in fp32 (pre-rounding h)
            }
            __syncthreads();
            if (tid < 192)
                cst(((u64*)(htn + (size_t)p0*12)) + tid, ((const u64*)hrow)[tid]);
        }
        if (t + 1 < NT) gbar(bar, bid);
    }

    // ---- final output write (full coverage, once) ----
    const int pbase = p0 + 16*w;
    #pragma unroll
    for (int s = 0; s < 3; ++s)
        out[pbase*12 + lane*3 + s] = osum[s];
}

extern "C" void kernel_launch(void* const* d_in, const int* in_sizes, int n_in,
                              void* d_out, int out_size, void* d_ws, size_t ws_size,
                              hipStream_t stream)
{
    (void)in_sizes; (void)n_in; (void)out_size; (void)ws_size;
    const float* x    = (const float*)d_in[0];
    const int*   ids  = (const int*)  d_in[1];
    const float* Wxg  = (const float*)d_in[2];
    const float* Whg  = (const float*)d_in[3];
    const float* bg   = (const float*)d_in[4];
    const float* Wxc  = (const float*)d_in[5];
    const float* Whc  = (const float*)d_in[6];
    const float* bc   = (const float*)d_in[7];
    float* out = (float*)d_out;

    char* base = (char*)d_ws;
    short*  bank  = (short*) (base);                 // 6,291,456 B
    short*  genh0 = (short*) (base + 6291456);       // 1,572,864
    short*  genh1 = (short*) (base + 7864320);       // 1,572,864
    short*  htmp0 = (short*) (base + 9437184);       // 1,572,864
    short*  htmp1 = (short*) (base + 11010048);      // 1,572,864
    bf16x8* wgt   = (bf16x8*)(base + 12582912);      // 110,592
    int*    bar   = (int*)   (base + 12693504);      // 16,384 (barrier state)

    hipMemsetAsync(bar, 0, 16384, stream);

    repack_kernel<<<27, 256, 0, stream>>>(Wxg, Whg, Wxc, Whc, wgt);

    fused_kernel<<<NBLK, 256, 0, stream>>>(x, ids, bank, genh0, genh1,
                                           htmp0, htmp1, wgt, bg, bc, bar, out);
}

// Round 10
// 1443.534 us; speedup vs baseline: 4.5458x; 1.8464x over previous
//
#include <hip/hip_runtime.h>
#include <hip/hip_bf16.h>

// ---- problem dims (fixed) ----
#define NCLS 4
#define BS   16
#define NT   32
#define OC   12
#define HW   4096
#define PIX  65536
#define STATE 786432        // PIX*OC
#define BANK  3145728       // NCLS*STATE

typedef short bf16x8 __attribute__((ext_vector_type(8)));
typedef float f32x4  __attribute__((ext_vector_type(4)));
typedef unsigned long long u64;

// jax.nn.hard_sigmoid = relu6(x+3)/6
__device__ __forceinline__ float hsig(float v){
    return fminf(fmaxf((v + 3.0f) * (1.0f/6.0f), 0.0f), 1.0f);
}
__device__ __forceinline__ short f2bf(float f){
    union { __hip_bfloat16 h; short s; } u;
    u.h = __float2bfloat16(f);   // RNE
    return u.s;
}

// =====================================================================
// Weight repack (verified R2): fragment-order bf16.
// wgt[cell][tap][kb][nt][lane], elem j = B[k=kb*32+(lane>>4)*8+j][n=nt*16+(lane&15)]
// =====================================================================
__global__ __launch_bounds__(256) void repack_kernel(
    const float* __restrict__ Wxg, const float* __restrict__ Whg,
    const float* __restrict__ Wxc, const float* __restrict__ Whc,
    bf16x8* __restrict__ wgt)
{
    int id = blockIdx.x * 256 + threadIdx.x;    // < 6912
    if (id >= 6912) return;
    int cell = id / 3456;
    int rem  = id - cell * 3456;
    int tap  = rem / 384;  rem -= tap * 384;
    int kb   = rem / 192;  rem -= kb * 192;
    int nt   = rem / 64;
    int lane = rem - nt * 64;
    int quad = lane >> 4;
    int n    = nt * 16 + (lane & 15);
    union { bf16x8 v; short s[8]; } o;
    #pragma unroll
    for (int j = 0; j < 8; ++j){
        int k = kb * 32 + quad * 8 + j;
        float f = 0.0f;
        if (cell == 0){
            if (k < 48)      f = Wxg[(tap*48 + k)*48 + n];
            else if (k < 60) f = Whg[(tap*12 + (k-48))*48 + n];
        } else {
            if (k < 24)      f = Wxc[(tap*24 + k)*48 + n];
            else if (k < 36) f = Whc[(tap*12 + (k-24))*48 + n];
        }
        o.s[j] = f2bf(f);
    }
    wgt[id] = o.v;
}

// frame f32 -> bf16 once (halves per-step frame traffic)
__global__ __launch_bounds__(256) void cvt_kernel(
    const float* __restrict__ x, short* __restrict__ xbf)
{
    for (int i = blockIdx.x*256 + threadIdx.x; i < 6291456; i += 2048*256){
        float4 f = ((const float4*)x)[i];
        union { u64 q; short s[4]; } pk;
        pk.s[0]=f2bf(f.x); pk.s[1]=f2bf(f.y); pk.s[2]=f2bf(f.z); pk.s[3]=f2bf(f.w);
        ((u64*)xbf)[i] = pk.q;
    }
}

// Pixel-major LDS records, 72 shorts (144B, 2-way-bank-free stride):
//   gen  : [0..47]=bank ch | [48..59]=h | [60..71]=0
//   class: [0..11]=frame | [12..23]=gen_h | [24..35]=class_h | [36..71]=0
#define REC 72

// XCD-aware row swizzle: XCD j gets a CONTIGUOUS band of 128 rows (2 images).
__device__ __forceinline__ int row_swizzle(int bid){
    return ((bid & 7) << 7) | (bid >> 3);
}

#define MFMA __builtin_amdgcn_mfma_f32_16x16x32_bf16

// =====================================================================
// One fused timestep: gen (3 redundant rows, 5-row halo) -> class (own row).
// All loads/stores normal cached ops; cross-timestep visibility comes from
// the hardware release/acquire at dispatch boundaries (R0-proven).
// =====================================================================
__global__ __launch_bounds__(256, 2) void step_kernel(
    const short* __restrict__ xbf,     // (BS,NT,HW,12) bf16
    const int*   __restrict__ ids, int t,
    short* __restrict__ bank,          // (PIX*48) bf16 flat (raw-reshape alias)
    const short* __restrict__ hin,  short* __restrict__ hnew,
    const short* __restrict__ htp,  short* __restrict__ htn,
    const float* __restrict__ gcs,  float* __restrict__ gcd,   // gen_c ping-pong
    float* __restrict__ class_c,
    const bf16x8* __restrict__ wgt,
    const float* __restrict__ bias_g, const float* __restrict__ bias_c,
    float* __restrict__ out)
{
    __shared__ __align__(16) short grec[5*66*REC];   // 47520 B (hosts zw later)
    __shared__ __align__(16) short crec[3*66*REC];   // 28512 B
    __shared__ __align__(8)  short hrow[768];        // 1536 B

    const int tid = threadIdx.x;
    const int rb  = row_swizzle(blockIdx.x);
    const int p0  = rb << 6;
    const int b   = p0 >> 12;
    const int y   = (p0 >> 6) & 63;
    const int lane = tid & 63, w = tid >> 6, m = lane & 15, quad = lane >> 4;
    const int colbase = 16*w + m;
    const int cid   = ids[t];
    const int cprev = (t > 0) ? ids[t-1] : -1;
    const bool slotmatch = (cprev >= 0) && ((b >> 2) == cprev);
    const bf16x8* wgt_cls = wgt + 3456;
    const short* xframe = xbf + (size_t)(b*NT + t)*(HW*12);
    // class_h source: slot cid content == htp when cid==cprev (refresh this
    // dispatch would race); both share the (BS,HW,12) p*12 indexing.
    const short* chs = (cid == cprev) ? htp : (bank + (size_t)cid*STATE);

    // ---- 1. zero-fill records ----
    {
        const uint4 z = make_uint4(0u,0u,0u,0u);
        uint4* g4 = (uint4*)grec;
        for (int j = tid; j < 2970; j += 256) g4[j] = z;
        uint4* c4 = (uint4*)crec;
        for (int j = tid; j < 1782; j += 256) c4[j] = z;
    }
    __syncthreads();

    // ---- 2. staging (normal cached loads) ----
    // gen: 5 halo rows (y-2..y+2) x 66 cols
    for (int pos = tid; pos < 330; pos += 256){
        int r = pos/66, c = pos - r*66;
        int yy = y + r - 2, xx = c - 1;
        if (yy >= 0 && yy < 64 && xx >= 0 && xx < 64){
            int p = (b<<12) + (yy<<6) + xx;
            const short* src = slotmatch ? (htp + (size_t)(p & 16383)*48)
                                         : (bank + (size_t)p*48);
            short* dst = &grec[pos*REC];
            uint4 v[6];
            #pragma unroll
            for (int q = 0; q < 6; ++q) v[q] = *(const uint4*)(src + q*8);
            #pragma unroll
            for (int q = 0; q < 6; ++q) *(uint4*)(dst + q*8) = v[q];
            *(u64*)(dst+48) = *(const u64*)(hin + (size_t)p*12);
            *(u64*)(dst+52) = *(const u64*)(hin + (size_t)p*12 + 4);
            *(u64*)(dst+56) = *(const u64*)(hin + (size_t)p*12 + 8);
            if (slotmatch && r == 2){      // own row: refresh bank (slot cprev)
                #pragma unroll
                for (int q = 0; q < 6; ++q)
                    *(uint4*)(bank + (size_t)p*48 + q*8) = v[q];
            }
        }
    }
    // class: 3 halo rows (y-1..y+1) x 66 cols — frame + class_h (ghn later)
    if (tid < 198){
        int pos = tid;
        int r = pos/66, c = pos - r*66;
        int yy = y + r - 1, xx = c - 1;
        if (yy >= 0 && yy < 64 && xx >= 0 && xx < 64){
            int p   = (b<<12) + (yy<<6) + xx;
            int pim = (yy<<6) + xx;
            short* dst = &crec[pos*REC];
            *(u64*)(dst+0)  = *(const u64*)(xframe + (size_t)pim*12);
            *(u64*)(dst+4)  = *(const u64*)(xframe + (size_t)pim*12 + 4);
            *(u64*)(dst+8)  = *(const u64*)(xframe + (size_t)pim*12 + 8);
            *(u64*)(dst+24) = *(const u64*)(chs + (size_t)p*12);
            *(u64*)(dst+28) = *(const u64*)(chs + (size_t)p*12 + 4);
            *(u64*)(dst+32) = *(const u64*)(chs + (size_t)p*12 + 8);
        }
    }
    __syncthreads();

    // ---- 3. gen MFMA: 3 output rows (y-1, y, y+1) ----
    f32x4 ga[3][3];
    #pragma unroll
    for (int rr = 0; rr < 3; ++rr){
        #pragma unroll
        for (int q = 0; q < 3; ++q){
            f32x4 zz = {0.f,0.f,0.f,0.f};
            ga[rr][q] = zz;
        }
    }
    #pragma unroll
    for (int rr = 0; rr < 3; ++rr){
        #pragma unroll
        for (int ky = 0; ky < 3; ++ky){
            #pragma unroll
            for (int kx = 0; kx < 3; ++kx){
                const int tap = ky*3 + kx;
                const int rec = ((rr+ky)*66 + colbase + kx)*REC;
                const bf16x8 a0 = *(const bf16x8*)&grec[rec + quad*8];
                const bf16x8 a1 = *(const bf16x8*)&grec[rec + 32 + quad*8];
                const bf16x8* wp0 = wgt + ((tap*2 + 0)*3)*64 + lane;
                const bf16x8* wp1 = wgt + ((tap*2 + 1)*3)*64 + lane;
                ga[rr][0] = MFMA(a0, wp0[0],   ga[rr][0], 0,0,0);
                ga[rr][1] = MFMA(a0, wp0[64],  ga[rr][1], 0,0,0);
                ga[rr][2] = MFMA(a0, wp0[128], ga[rr][2], 0,0,0);
                ga[rr][0] = MFMA(a1, wp1[0],   ga[rr][0], 0,0,0);
                ga[rr][1] = MFMA(a1, wp1[64],  ga[rr][1], 0,0,0);
                ga[rr][2] = MFMA(a1, wp1[128], ga[rr][2], 0,0,0);
            }
        }
    }
    __syncthreads();          // grec reads done -> zw overlays grec

    // ---- 4. gen epilogues: LSTM + ghn into crec, own row -> hrow ----
    float* zw = ((float*)grec) + w * 768;        // wave-private 3 KB
    #pragma unroll
    for (int rr = 0; rr < 3; ++rr){
        int oy = y + rr - 1;
        if (oy < 0 || oy > 63) continue;         // block-uniform
        #pragma unroll
        for (int r2 = 0; r2 < 4; ++r2){
            zw[(quad*4 + r2)*48 +      m] = ga[rr][0][r2];
            zw[(quad*4 + r2)*48 + 16 + m] = ga[rr][1][r2];
            zw[(quad*4 + r2)*48 + 32 + m] = ga[rr][2][r2];
        }
        __syncthreads();
        const int obase = (b<<12) + (oy<<6) + 16*w;
        #pragma unroll
        for (int s = 0; s < 3; ++s){
            int idx = lane*3 + s;
            int px  = idx / 12;
            int j   = idx - px*12;
            float zi = zw[px*48 +      j] + bias_g[j];
            float zf = zw[px*48 + 12 + j] + bias_g[12 + j];
            float zg = zw[px*48 + 24 + j] + bias_g[24 + j];
            float zo = zw[px*48 + 36 + j] + bias_g[36 + j];
            int off = obase*12 + idx;
            float cold = gcs[off];
            float cn = hsig(zf)*cold + hsig(zi)*tanhf(zg);
            if (rr == 1) gcd[off] = cn;          // persist own row only
            float h = hsig(zo)*tanhf(cn);
            crec[(rr*66 + 16*w + px + 1)*REC + 12 + j] = f2bf(h);
            if (rr == 1) hrow[w*192 + idx] = f2bf(h);
        }
        __syncthreads();
    }
    __syncthreads();          // crec ghn + hrow complete

    // ---- 5. hnew global write + class MFMA ----
    if (tid < 192)
        ((u64*)(hnew + (size_t)p0*12))[tid] = ((const u64*)hrow)[tid];

    f32x4 ca[3];
    {
        f32x4 zz = {0.f,0.f,0.f,0.f};
        ca[0] = zz; ca[1] = zz; ca[2] = zz;
    }
    #pragma unroll
    for (int ky = 0; ky < 3; ++ky){
        #pragma unroll
        for (int kx = 0; kx < 3; ++kx){
            const int tap = ky*3 + kx;
            const int rec = (ky*66 + colbase + kx)*REC;
            const bf16x8 a0 = *(const bf16x8*)&crec[rec + quad*8];
            const bf16x8 a1 = *(const bf16x8*)&crec[rec + 32 + quad*8];
            const bf16x8* wp0 = wgt_cls + ((tap*2 + 0)*3)*64 + lane;
            const bf16x8* wp1 = wgt_cls + ((tap*2 + 1)*3)*64 + lane;
            ca[0] = MFMA(a0, wp0[0],   ca[0], 0,0,0);
            ca[1] = MFMA(a0, wp0[64],  ca[1], 0,0,0);
            ca[2] = MFMA(a0, wp0[128], ca[2], 0,0,0);
            ca[0] = MFMA(a1, wp1[0],   ca[0], 0,0,0);
            ca[1] = MFMA(a1, wp1[64],  ca[1], 0,0,0);
            ca[2] = MFMA(a1, wp1[128], ca[2], 0,0,0);
        }
    }
    __syncthreads();          // hrow reads + crec reads done

    // ---- 6. class epilogue ----
    #pragma unroll
    for (int r2 = 0; r2 < 4; ++r2){
        zw[(quad*4 + r2)*48 +      m] = ca[0][r2];
        zw[(quad*4 + r2)*48 + 16 + m] = ca[1][r2];
        zw[(quad*4 + r2)*48 + 32 + m] = ca[2][r2];
    }
    __syncthreads();
    {
        float* cc = class_c + (size_t)cid * STATE;
        const int obase = p0 + 16*w;
        #pragma unroll
        for (int s = 0; s < 3; ++s){
            int idx = lane*3 + s;
            int px  = idx / 12;
            int j   = idx - px*12;
            float zi = zw[px*48 +      j] + bias_c[j];
            float zf = zw[px*48 + 12 + j] + bias_c[12 + j];
            float zg = zw[px*48 + 24 + j] + bias_c[24 + j];
            float zo = zw[px*48 + 36 + j] + bias_c[36 + j];
            int off = obase*12 + idx;
            float cold = cc[off];
            float cn = hsig(zf)*cold + hsig(zi)*tanhf(zg);
            cc[off] = cn;
            float h = hsig(zo)*tanhf(cn);
            out[off] += h;               // time-sum in fp32
            hrow[w*192 + idx] = f2bf(h);
        }
    }
    __syncthreads();
    if (tid < 192)
        ((u64*)(htn + (size_t)p0*12))[tid] = ((const u64*)hrow)[tid];
}

extern "C" void kernel_launch(void* const* d_in, const int* in_sizes, int n_in,
                              void* d_out, int out_size, void* d_ws, size_t ws_size,
                              hipStream_t stream)
{
    (void)in_sizes; (void)n_in; (void)out_size; (void)ws_size;
    const float* x    = (const float*)d_in[0];
    const int*   ids  = (const int*)  d_in[1];
    const float* Wxg  = (const float*)d_in[2];
    const float* Whg  = (const float*)d_in[3];
    const float* bg   = (const float*)d_in[4];
    const float* Wxc  = (const float*)d_in[5];
    const float* Whc  = (const float*)d_in[6];
    const float* bc   = (const float*)d_in[7];
    float* out = (float*)d_out;

    char* base = (char*)d_ws;
    short*  bank    = (short*) (base);                // 6,291,456
    short*  genh0   = (short*) (base + 6291456);      // 1,572,864
    short*  genh1   = (short*) (base + 7864320);      // 1,572,864
    short*  htmp0   = (short*) (base + 9437184);      // 1,572,864
    short*  htmp1   = (short*) (base + 11010048);     // 1,572,864
    float*  gen_cA  = (float*) (base + 12582912);     // 3,145,728
    float*  gen_cB  = (float*) (base + 15728640);     // 3,145,728
    float*  class_c = (float*) (base + 18874368);     // 12,582,912
    bf16x8* wgt     = (bf16x8*)(base + 31457280);     // 110,592
    short*  xbf     = (short*) (base + 31567872);     // 50,331,648 (ends ~81.9MB)

    hipMemsetAsync(bank,    0, 6291456,  stream);
    hipMemsetAsync(genh0,   0, 1572864,  stream);
    hipMemsetAsync(gen_cA,  0, 3145728,  stream);
    hipMemsetAsync(class_c, 0, 12582912, stream);
    hipMemsetAsync(out,     0, 3145728,  stream);

    repack_kernel<<<27, 256, 0, stream>>>(Wxg, Whg, Wxc, Whc, wgt);
    cvt_kernel<<<2048, 256, 0, stream>>>(x, xbf);

    for (int t = 0; t < NT; ++t){
        short* hin = (t & 1) ? genh1 : genh0;
        short* hnw = (t & 1) ? genh0 : genh1;
        short* htp = (t & 1) ? htmp0 : htmp1;
        short* htn = (t & 1) ? htmp1 : htmp0;
        float* gcs = (t & 1) ? gen_cB : gen_cA;
        float* gcd = (t & 1) ? gen_cA : gen_cB;
        step_kernel<<<1024, 256, 0, stream>>>(xbf, ids, t, bank,
                                              hin, hnw, htp, htn,
                                              gcs, gcd, class_c,
                                              wgt, bg, bc, out);
    }
}